// Round 1
// baseline (1116.314 us; speedup 1.0000x reference)
//
#include <hip/hip_runtime.h>

// PolicyHead (KataGo-style) for MI355X.
// K1: y = x @ [w_p | w_g]  (M=739328, K=256, N=64) fp32 vector-FMA GEMM.
//     p-half -> ws; g-half -> BN+relu -> per-image sum/max pool (shfl + atomics).
// K2: per-image bias = g_pooled @ w_bias + b_bias; pass logits -> out directly.
// K3: p + bias -> BN -> relu -> @ w_out -> out (memory-bound epilogue).

#define N_IMG 2048
#define HW    361
#define CIN   256
#define C     32
#define NPIX  (N_IMG * HW)        // 739328 (exactly 2888 * 256)
#define EPSV  1e-3f

#define MT 256                    // pixels per block (K1)
#define KT 32                     // k-tile
#define NT 64                     // all 64 output channels

// workspace layout (float offsets)
#define WS_P_OFF    0                         // [NPIX][32]      94.6 MB
#define WS_PSUM_OFF ((size_t)NPIX * 32)       // [2048][32]
#define WS_PMAX_OFF (WS_PSUM_OFF + (size_t)N_IMG * C)
#define WS_BIAS_OFF (WS_PMAX_OFF + (size_t)N_IMG * C)
// total = 23,855,104 floats = 95.4 MB

__global__ __launch_bounds__(256, 2) void k1_gemm_pool(
    const float* __restrict__ x,
    const float* __restrict__ w_p, const float* __restrict__ w_g,
    const float* __restrict__ beta_g, const float* __restrict__ mean_g,
    const float* __restrict__ var_g, float* __restrict__ ws)
{
    __shared__ float xs[KT][MT];   // 32 KB, transposed x tile
    __shared__ float wsh[KT][NT];  // 8 KB

    const int t  = threadIdx.x;
    const int tm = t >> 3;         // 0..31 : pixel-row group (8 px each)
    const int tn = t & 7;          // 0..7  : channel group (8 ch each)
    const long P0 = (long)blockIdx.x * MT;

    float acc[8][8];
#pragma unroll
    for (int i = 0; i < 8; ++i)
#pragma unroll
        for (int j = 0; j < 8; ++j) acc[i][j] = 0.f;

    const float* xrow = x + (P0 + t) * (long)CIN;  // this thread stages pixel P0+t
    const int wr = t >> 3, wpart = t & 7;          // w staging role

    for (int k0 = 0; k0 < CIN; k0 += KT) {
        // stage x[P0..P0+256][k0..k0+32] transposed -> xs[kk][m]
#pragma unroll
        for (int i = 0; i < KT / 4; ++i) {
            float4 v = *(const float4*)(xrow + k0 + i * 4);
            xs[i * 4 + 0][t] = v.x;
            xs[i * 4 + 1][t] = v.y;
            xs[i * 4 + 2][t] = v.z;
            xs[i * 4 + 3][t] = v.w;
        }
        // stage W tile: row wr (0..31), cols wpart*8..+8  (cols<32: w_p, else w_g)
        {
            const float* src = (wpart < 4) ? (w_p + (long)(k0 + wr) * C + wpart * 8)
                                           : (w_g + (long)(k0 + wr) * C + (wpart - 4) * 8);
            float4 v0 = *(const float4*)(src);
            float4 v1 = *(const float4*)(src + 4);
            *(float4*)(&wsh[wr][wpart * 8])     = v0;
            *(float4*)(&wsh[wr][wpart * 8 + 4]) = v1;
        }
        __syncthreads();
#pragma unroll
        for (int kk = 0; kk < KT; ++kk) {
            float a[8], b[8];
            *(float4*)(a)     = *(const float4*)(&xs[kk][tm * 8]);
            *(float4*)(a + 4) = *(const float4*)(&xs[kk][tm * 8 + 4]);
            *(float4*)(b)     = *(const float4*)(&wsh[kk][tn * 8]);
            *(float4*)(b + 4) = *(const float4*)(&wsh[kk][tn * 8 + 4]);
#pragma unroll
            for (int i = 0; i < 8; ++i)
#pragma unroll
                for (int j = 0; j < 8; ++j)
                    acc[i][j] = fmaf(a[i], b[j], acc[i][j]);
        }
        __syncthreads();
    }

    // ---- epilogue ----
    if (tn < 4) {
        // p channels (tn*8+j in 0..31): spill to ws
        float* wp_out = ws + WS_P_OFF;
#pragma unroll
        for (int i = 0; i < 8; ++i) {
            long pix = P0 + tm * 8 + i;
            float4 v0 = make_float4(acc[i][0], acc[i][1], acc[i][2], acc[i][3]);
            float4 v1 = make_float4(acc[i][4], acc[i][5], acc[i][6], acc[i][7]);
            *(float4*)(wp_out + pix * 32 + tn * 8)     = v0;
            *(float4*)(wp_out + pix * 32 + tn * 8 + 4) = v1;
        }
    }

    // g channels: BN + relu + per-image pooling. Block spans at most 2 images
    // (MT=256 < HW=361). seg 0 = image n0, seg 1 = image n0+1.
    float gsum[2][8], gmax[2][8];
#pragma unroll
    for (int s = 0; s < 2; ++s)
#pragma unroll
        for (int j = 0; j < 8; ++j) { gsum[s][j] = 0.f; gmax[s][j] = 0.f; }

    const int  n0 = (int)(P0 / HW);
    const long Bnd = (long)(n0 + 1) * HW;  // first pixel of next image

    if (tn >= 4) {
#pragma unroll
        for (int j = 0; j < 8; ++j) {
            int c = (tn - 4) * 8 + j;
            float rs = rsqrtf(var_g[c] + EPSV);
            float mg = mean_g[c], bg = beta_g[c];
#pragma unroll
            for (int i = 0; i < 8; ++i) {
                long pix = P0 + tm * 8 + i;
                float g = fmaxf((acc[i][j] - mg) * rs + bg, 0.f);
                int s = (pix >= Bnd) ? 1 : 0;
                gsum[s][j] += g;
                gmax[s][j] = fmaxf(gmax[s][j], g);
            }
        }
    }

    // butterfly-reduce across the 8 tm-lanes within each wave (lane bits 3..5);
    // all threads execute (uniform control flow), p-threads carry zeros.
#pragma unroll
    for (int s = 0; s < 2; ++s)
#pragma unroll
        for (int j = 0; j < 8; ++j) {
            float v = gsum[s][j], m = gmax[s][j];
            v += __shfl_xor(v, 8, 64);  m = fmaxf(m, __shfl_xor(m, 8, 64));
            v += __shfl_xor(v, 16, 64); m = fmaxf(m, __shfl_xor(m, 16, 64));
            v += __shfl_xor(v, 32, 64); m = fmaxf(m, __shfl_xor(m, 32, 64));
            gsum[s][j] = v; gmax[s][j] = m;
        }

    const int lane = t & 63;
    if (tn >= 4 && (lane >> 3) == 0) {   // one lane per (wave, channel-group)
        float* psum = ws + WS_PSUM_OFF;
        int*   pmax = (int*)(ws + WS_PMAX_OFF);
#pragma unroll
        for (int s = 0; s < 2; ++s) {
            int n = n0 + s;
            bool active = (s == 0) || (Bnd < P0 + MT && n < N_IMG);
            if (active) {
#pragma unroll
                for (int j = 0; j < 8; ++j) {
                    int c = (tn - 4) * 8 + j;
                    atomicAdd(psum + n * C + c, gsum[s][j]);
                    // relu output >= 0, and buffer init 0 -> int-compare max is valid
                    atomicMax(pmax + n * C + c, __float_as_int(gmax[s][j]));
                }
            }
        }
    }
}

__global__ void k2_bias(const float* __restrict__ psum,
                        const float* __restrict__ pmax,
                        const float* __restrict__ w_bias,  // [64][32]
                        const float* __restrict__ b_bias,  // [32]
                        const float* __restrict__ w_pass,  // [64][2]
                        const float* __restrict__ b_pass,  // [2]
                        float* __restrict__ ws_bias,       // [2048][32]
                        float* __restrict__ out)
{
    const int n = blockIdx.x;
    const int t = threadIdx.x;  // 64 threads
    __shared__ float gp[64];
    if (t < 32) gp[t] = psum[n * 32 + t] * (1.f / (float)HW);
    else        gp[t] = pmax[n * 32 + (t - 32)];
    __syncthreads();
    if (t < 32) {
        float acc = b_bias[t];
#pragma unroll
        for (int j = 0; j < 64; ++j) acc = fmaf(gp[j], w_bias[j * 32 + t], acc);
        ws_bias[n * 32 + t] = acc;
    } else if (t < 34) {
        int k = t - 32;
        float acc = b_pass[k] - 3.0f;
#pragma unroll
        for (int j = 0; j < 64; ++j) acc = fmaf(gp[j], w_pass[j * 2 + k], acc);
        out[(size_t)k * ((size_t)N_IMG * 362) + (size_t)n * 362 + 361] = acc;
    }
}

__global__ __launch_bounds__(256) void k3_epilogue(
    const float* __restrict__ ws_p, const float* __restrict__ ws_bias,
    const float* __restrict__ beta_p, const float* __restrict__ mean_p,
    const float* __restrict__ var_p, const float* __restrict__ w_out,
    float* __restrict__ out)
{
    const long pix = (long)blockIdx.x * 256 + threadIdx.x;  // exact grid, no tail
    const int n  = (int)(pix / HW);
    const int hw = (int)(pix - (long)n * HW);

    float p[32], b[32];
    const float4* pr = (const float4*)(ws_p + pix * 32);
    const float4* br = (const float4*)(ws_bias + (long)n * 32);
#pragma unroll
    for (int i = 0; i < 8; ++i) ((float4*)p)[i] = pr[i];
#pragma unroll
    for (int i = 0; i < 8; ++i) ((float4*)b)[i] = br[i];

    float a0 = 0.f, a1 = 0.f;
#pragma unroll
    for (int c = 0; c < 32; ++c) {
        float v = (p[c] + b[c] - mean_p[c]) * rsqrtf(var_p[c] + EPSV) + beta_p[c];
        v = fmaxf(v, 0.f);
        a0 = fmaf(v, w_out[c * 2 + 0], a0);
        a1 = fmaf(v, w_out[c * 2 + 1], a1);
    }
    out[(size_t)n * 362 + hw] = a0;
    out[(size_t)N_IMG * 362 + (size_t)n * 362 + hw] = a1;
}

extern "C" void kernel_launch(void* const* d_in, const int* in_sizes, int n_in,
                              void* d_out, int out_size, void* d_ws, size_t ws_size,
                              hipStream_t stream)
{
    const float* x      = (const float*)d_in[0];
    const float* w_p    = (const float*)d_in[1];
    const float* w_g    = (const float*)d_in[2];
    const float* beta_g = (const float*)d_in[3];
    const float* mean_g = (const float*)d_in[4];
    const float* var_g  = (const float*)d_in[5];
    const float* w_bias = (const float*)d_in[6];
    const float* b_bias = (const float*)d_in[7];
    const float* beta_p = (const float*)d_in[8];
    const float* mean_p = (const float*)d_in[9];
    const float* var_p  = (const float*)d_in[10];
    const float* w_out  = (const float*)d_in[11];
    const float* w_pass = (const float*)d_in[12];
    const float* b_pass = (const float*)d_in[13];
    float* out = (float*)d_out;
    float* ws  = (float*)d_ws;
    (void)in_sizes; (void)n_in; (void)out_size; (void)ws_size;

    // zero the pool accumulators (sum + max, contiguous) every call
    hipMemsetAsync(ws + WS_PSUM_OFF, 0, 2u * N_IMG * C * sizeof(float), stream);

    k1_gemm_pool<<<NPIX / MT, 256, 0, stream>>>(x, w_p, w_g, beta_g, mean_g, var_g, ws);
    k2_bias<<<N_IMG, 64, 0, stream>>>(ws + WS_PSUM_OFF, ws + WS_PMAX_OFF,
                                      w_bias, b_bias, w_pass, b_pass,
                                      ws + WS_BIAS_OFF, out);
    k3_epilogue<<<NPIX / 256, 256, 0, stream>>>(ws + WS_P_OFF, ws + WS_BIAS_OFF,
                                                beta_p, mean_p, var_p, w_out, out);
}

// Round 4
// 1040.698 us; speedup vs baseline: 1.0727x; 1.0727x over previous
//
#include <hip/hip_runtime.h>
#include <hip/hip_bf16.h>

// PolicyHead (KataGo-style) for MI355X — round 2 kernel (resubmit x2: GPU
// acquisition timed out both attempts; kernel has never run).
// K0 (prep): split w_p|w_g fp32 -> bf16 hi/lo, transposed [64 cols][264 k-pad].
// K1: y = x @ [w_p|w_g] via 3-term bf16-split MFMA (hi*hi + lo*hi + hi*lo).
//     A (x) global->reg->cvt, no LDS. B staged in padded LDS once per block.
//     p-half -> ws; g-half -> BN+relu -> per-image sum/max pool (shfl+atomics).
// K2: per image: bias GEMV + pass logits + p-epilogue (BN+relu+w_out) -> out.

#define N_IMG 2048
#define HW    361
#define CIN   256
#define C     32
#define NPIX  (N_IMG * HW)            // 739328 = 2888*256 = 1444*512
#define EPSV  1e-3f
#define OUT_HALF (N_IMG * 362)        // 741376

#define KPAD  264                     // 256 + 8 bf16 pad (row stride 528 B)

// workspace layout (float offsets)
#define WS_P_OFF    0                               // [NPIX][32] fp32, 94.6 MB
#define WS_PSUM_OFF ((size_t)NPIX * 32)             // [2048][32]
#define WS_PMAX_OFF (WS_PSUM_OFF + (size_t)N_IMG * C)
#define WS_WT_OFF   (WS_PMAX_OFF + (size_t)N_IMG * C)  // [2][64][264] ushort

typedef __attribute__((ext_vector_type(8))) short short8;
typedef __attribute__((ext_vector_type(4))) float f32x4;

static __device__ __forceinline__ short f2bf(float f) {
    __hip_bfloat16 h = __float2bfloat16(f);   // RTNE, v_cvt hw op
    return *reinterpret_cast<short*>(&h);
}
static __device__ __forceinline__ float bf2f(short s) {
    unsigned int u = ((unsigned int)(unsigned short)s) << 16;
    return __builtin_bit_cast(float, u);
}

// ---- K0: weight split/transpose prep --------------------------------------
__global__ void k0_prep(const float* __restrict__ w_p, const float* __restrict__ w_g,
                        unsigned short* __restrict__ wt)   // [2][64][KPAD]
{
    const int col = blockIdx.x;           // 0..63 output channel
    const int t = threadIdx.x;            // 256
#pragma unroll
    for (int it = 0; it < 2; ++it) {
        int kk = t + it * 256;
        if (kk < KPAD) {
            unsigned short hi = 0, lo = 0;
            if (kk < CIN) {
                float f = (col < C) ? w_p[kk * C + col] : w_g[kk * C + (col - C)];
                short h = f2bf(f);
                hi = (unsigned short)h;
                lo = (unsigned short)f2bf(f - bf2f(h));
            }
            wt[col * KPAD + kk] = hi;
            wt[64 * KPAD + col * KPAD + kk] = lo;
        }
    }
}

// ---- K1: main GEMM + g pooling --------------------------------------------
__global__ __launch_bounds__(256, 2) void k1_gemm_pool(
    const float* __restrict__ x,
    const unsigned short* __restrict__ wt_g,   // [2][64][KPAD] pre-split
    const float* __restrict__ beta_g, const float* __restrict__ mean_g,
    const float* __restrict__ var_g,
    float* __restrict__ ws_p, float* __restrict__ psum, int* __restrict__ pmax)
{
    __shared__ uint4 smem4[2 * 64 * KPAD * 2 / 16];     // 67584 B
    const unsigned short* wt_hi_l = (const unsigned short*)smem4;
    const unsigned short* wt_lo_l = wt_hi_l + 64 * KPAD;

    const int t = threadIdx.x;
    // stage both weight halves (linear copy, 67584 B = 4224 uint4)
    {
        const uint4* src = (const uint4*)wt_g;
        for (int i = t; i < 4224; i += 256) smem4[i] = src[i];
    }
    __syncthreads();

    const int wave = t >> 6, lane = t & 63;
    const int lr = lane & 15, lk = lane >> 4;
    const int W0 = blockIdx.x * 256 + wave * 64;     // wave's first pixel

    f32x4 acc[4][4];
#pragma unroll
    for (int m = 0; m < 4; ++m)
#pragma unroll
        for (int n = 0; n < 4; ++n) acc[m][n] = (f32x4){0.f, 0.f, 0.f, 0.f};

    const float* ap = x + (size_t)(W0 + lr) * CIN + lk * 8;

    for (int k0 = 0; k0 < CIN; k0 += 32) {
        // A: 4 pixel-groups x 8 consecutive k fp32 (fully coalesced)
        float4 av[4][2];
#pragma unroll
        for (int m = 0; m < 4; ++m) {
            const float* p = ap + (size_t)m * 16 * CIN + k0;
            av[m][0] = *(const float4*)p;
            av[m][1] = *(const float4*)(p + 4);
        }
        // B: hi/lo fragments from padded LDS (2-way banks, free)
        short8 bh[4], bl[4];
#pragma unroll
        for (int n = 0; n < 4; ++n) {
            int idx = (n * 16 + lr) * KPAD + k0 + lk * 8;
            bh[n] = *(const short8*)(wt_hi_l + idx);
            bl[n] = *(const short8*)(wt_lo_l + idx);
        }
        // split A into hi/lo bf16
        short8 ah[4], al[4];
#pragma unroll
        for (int m = 0; m < 4; ++m) {
            float fa[8];
            *(float4*)(fa) = av[m][0]; *(float4*)(fa + 4) = av[m][1];
#pragma unroll
            for (int j = 0; j < 8; ++j) {
                short h = f2bf(fa[j]);
                ah[m][j] = h;
                al[m][j] = f2bf(fa[j] - bf2f(h));
            }
        }
        // 3-term MFMA: hi*hi + lo*hi + hi*lo  (lo*lo dropped, ~2^-16 rel)
#pragma unroll
        for (int m = 0; m < 4; ++m)
#pragma unroll
            for (int n = 0; n < 4; ++n) {
                acc[m][n] = __builtin_amdgcn_mfma_f32_16x16x32_bf16(ah[m], bh[n], acc[m][n], 0, 0, 0);
                acc[m][n] = __builtin_amdgcn_mfma_f32_16x16x32_bf16(al[m], bh[n], acc[m][n], 0, 0, 0);
                acc[m][n] = __builtin_amdgcn_mfma_f32_16x16x32_bf16(ah[m], bl[n], acc[m][n], 0, 0, 0);
            }
    }

    // ---- epilogue ----
    // D layout: col = lane&15 -> channel nr*16+lr ; row = (lane>>4)*4+r -> pixel
    // p channels (n_rep 0,1): raw conv out -> ws_p[pix][ch]
#pragma unroll
    for (int m = 0; m < 4; ++m)
#pragma unroll
        for (int n = 0; n < 2; ++n)
#pragma unroll
            for (int r = 0; r < 4; ++r) {
                int pix = W0 + m * 16 + lk * 4 + r;
                ws_p[(size_t)pix * 32 + n * 16 + lr] = acc[m][n][r];
            }

    // g channels (n_rep 2,3): BN + relu + per-image pool.
    // Wave spans <= 2 images (64 < 361). Compile-time seg accumulators
    // (runtime-indexed arrays would spill to scratch — rule #20).
    const int n0w = W0 / HW;
    const int Bnd = (n0w + 1) * HW;
    float gs0[2] = {0.f, 0.f}, gs1[2] = {0.f, 0.f};
    float gm0[2] = {0.f, 0.f}, gm1[2] = {0.f, 0.f};
#pragma unroll
    for (int n = 0; n < 2; ++n) {
        const int cg = n * 16 + lr;
        const float rs = rsqrtf(var_g[cg] + EPSV);
        const float mg = mean_g[cg], bg = beta_g[cg];
#pragma unroll
        for (int m = 0; m < 4; ++m)
#pragma unroll
            for (int r = 0; r < 4; ++r) {
                int pix = W0 + m * 16 + lk * 4 + r;
                float g = fmaxf((acc[m][n + 2][r] - mg) * rs + bg, 0.f);
                bool s1 = (pix >= Bnd);
                gs0[n] += s1 ? 0.f : g;
                gs1[n] += s1 ? g : 0.f;
                gm0[n] = fmaxf(gm0[n], s1 ? 0.f : g);
                gm1[n] = fmaxf(gm1[n], s1 ? g : 0.f);
            }
    }
    // reduce across the 4 lk-lanes sharing a channel (lane bits 4,5)
#pragma unroll
    for (int n = 0; n < 2; ++n) {
        gs0[n] += __shfl_xor(gs0[n], 16, 64); gs0[n] += __shfl_xor(gs0[n], 32, 64);
        gs1[n] += __shfl_xor(gs1[n], 16, 64); gs1[n] += __shfl_xor(gs1[n], 32, 64);
        gm0[n] = fmaxf(gm0[n], __shfl_xor(gm0[n], 16, 64));
        gm0[n] = fmaxf(gm0[n], __shfl_xor(gm0[n], 32, 64));
        gm1[n] = fmaxf(gm1[n], __shfl_xor(gm1[n], 16, 64));
        gm1[n] = fmaxf(gm1[n], __shfl_xor(gm1[n], 32, 64));
    }
    if (lk == 0) {
#pragma unroll
        for (int n = 0; n < 2; ++n) {
            int c = n * 16 + lr;
            atomicAdd(psum + n0w * C + c, gs0[n]);
            atomicMax(pmax + n0w * C + c, __float_as_int(gm0[n]));  // relu>=0
        }
        if (Bnd < W0 + 64) {
#pragma unroll
            for (int n = 0; n < 2; ++n) {
                int c = n * 16 + lr;
                atomicAdd(psum + (n0w + 1) * C + c, gs1[n]);
                atomicMax(pmax + (n0w + 1) * C + c, __float_as_int(gm1[n]));
            }
        }
    }
}

// ---- K2: per-image bias GEMV + pass logits + p epilogue -------------------
__global__ __launch_bounds__(256) void k2_epilogue(
    const float* __restrict__ psum, const int* __restrict__ pmax,
    const float* __restrict__ w_bias, const float* __restrict__ b_bias,
    const float* __restrict__ w_pass, const float* __restrict__ b_pass,
    const float* __restrict__ beta_p, const float* __restrict__ mean_p,
    const float* __restrict__ var_p, const float* __restrict__ w_out,
    const float* __restrict__ ws_p, float* __restrict__ out)
{
    const int n = blockIdx.x;
    const int t = threadIdx.x;
    __shared__ float gp[64];
    __shared__ float rs_s[32], off_s[32], wo0_s[32], wo1_s[32];

    if (t < 32)      gp[t] = psum[n * 32 + t] * (1.0f / (float)HW);
    else if (t < 64) gp[t] = __int_as_float(pmax[n * 32 + (t - 32)]);
    __syncthreads();

    if (t < 32) {
        float bias = b_bias[t];
#pragma unroll
        for (int j = 0; j < 64; ++j) bias = fmaf(gp[j], w_bias[j * 32 + t], bias);
        float rs = rsqrtf(var_p[t] + EPSV);
        rs_s[t] = rs;
        off_s[t] = (bias - mean_p[t]) * rs + beta_p[t];
        wo0_s[t] = w_out[t * 2 + 0];
        wo1_s[t] = w_out[t * 2 + 1];
    } else if (t < 34) {
        int k = t - 32;
        float a = b_pass[k] - 3.0f;
#pragma unroll
        for (int j = 0; j < 64; ++j) a = fmaf(gp[j], w_pass[j * 2 + k], a);
        out[(size_t)k * OUT_HALF + (size_t)n * 362 + 361] = a;
    }
    __syncthreads();

    for (int i = t; i < HW; i += 256) {
        const float* pr = ws_p + ((size_t)n * HW + i) * 32;
        float p[32];
#pragma unroll
        for (int q = 0; q < 8; ++q) ((float4*)p)[q] = ((const float4*)pr)[q];
        float a0 = 0.f, a1 = 0.f;
#pragma unroll
        for (int c = 0; c < 32; ++c) {
            float v = fmaxf(fmaf(p[c], rs_s[c], off_s[c]), 0.f);
            a0 = fmaf(v, wo0_s[c], a0);
            a1 = fmaf(v, wo1_s[c], a1);
        }
        out[(size_t)n * 362 + i] = a0;
        out[(size_t)OUT_HALF + (size_t)n * 362 + i] = a1;
    }
}

extern "C" void kernel_launch(void* const* d_in, const int* in_sizes, int n_in,
                              void* d_out, int out_size, void* d_ws, size_t ws_size,
                              hipStream_t stream)
{
    const float* x      = (const float*)d_in[0];
    const float* w_p    = (const float*)d_in[1];
    const float* w_g    = (const float*)d_in[2];
    const float* beta_g = (const float*)d_in[3];
    const float* mean_g = (const float*)d_in[4];
    const float* var_g  = (const float*)d_in[5];
    const float* w_bias = (const float*)d_in[6];
    const float* b_bias = (const float*)d_in[7];
    const float* beta_p = (const float*)d_in[8];
    const float* mean_p = (const float*)d_in[9];
    const float* var_p  = (const float*)d_in[10];
    const float* w_out  = (const float*)d_in[11];
    const float* w_pass = (const float*)d_in[12];
    const float* b_pass = (const float*)d_in[13];
    float* out = (float*)d_out;
    float* ws  = (float*)d_ws;
    (void)in_sizes; (void)n_in; (void)out_size; (void)ws_size;

    // zero pool accumulators (psum + pmax contiguous)
    hipMemsetAsync(ws + WS_PSUM_OFF, 0, 2u * N_IMG * C * sizeof(float), stream);

    k0_prep<<<64, 256, 0, stream>>>(w_p, w_g, (unsigned short*)(ws + WS_WT_OFF));
    k1_gemm_pool<<<NPIX / 256, 256, 0, stream>>>(
        x, (const unsigned short*)(ws + WS_WT_OFF), beta_g, mean_g, var_g,
        ws + WS_P_OFF, ws + WS_PSUM_OFF, (int*)(ws + WS_PMAX_OFF));
    k2_epilogue<<<N_IMG, 256, 0, stream>>>(
        ws + WS_PSUM_OFF, (const int*)(ws + WS_PMAX_OFF),
        w_bias, b_bias, w_pass, b_pass, beta_p, mean_p, var_p, w_out,
        ws + WS_P_OFF, out);
}